// Round 7
// baseline (51.689 us; speedup 1.0000x reference)
//
#include <hip/hip_runtime.h>
#include <hip/hip_bf16.h>
#include <math.h>

#define HDIM 150

typedef __bf16 bf16x8 __attribute__((ext_vector_type(8)));
typedef __bf16 bf16x4 __attribute__((ext_vector_type(4)));
typedef float  f32x4  __attribute__((ext_vector_type(4)));

// ---------------------------------------------------------------------------
// fully unrolled Batcher odd-even mergesort, n = 16
// ---------------------------------------------------------------------------
__device__ __forceinline__ void cswap(float& a, float& b) {
    float lo = fminf(a, b);
    float hi = fmaxf(a, b);
    a = lo; b = hi;
}

__device__ __forceinline__ void sort16(float v[16]) {
#pragma unroll
    for (int pp = 1; pp < 16; pp <<= 1) {
#pragma unroll
        for (int k = pp; k >= 1; k >>= 1) {
#pragma unroll
            for (int j = k & (pp - 1); j + k < 16; j += 2 * k) {
#pragma unroll
                for (int i = 0; i < k; ++i) {
                    if ((i + j) / (2 * pp) == (i + j + k) / (2 * pp))
                        cswap(v[i + j], v[i + j + k]);
                }
            }
        }
    }
}

// ---------------------------------------------------------------------------
// k_all R15: R14 single-kernel with the x-gather latency chain hoisted IN
// FRONT of the prologue.
//  * rg[] loaded first; x tiles 0..3 issued into a 4-deep register ring
//    BEFORE weight staging (loads cannot be hoisted across s_barrier by the
//    compiler, so R14 serialized prologue -> first x load; now the ~1500cyc
//    prologue runs under the x/kmer/emb memory latency).
//  * main loop prefetches tile t+4 after consuming tile t (4-deep steady
//    state ~1200cyc cover vs ~300cyc/tile compute; counted vmcnt by compiler).
//
// LDS overlay (39424 B -> 4 blocks/CU):
//   R0 [0,24000): phase A = W1|b1@2700|W2@2850 staging (16.2KB)
//                 phase B = sH (32*264 bf16 = 16896 B)
//                 phase D = W3 staging (6000 f32 = 24000 B)
//   R1 [24064,39424): phase A = fragment blob (15 tiles x 1KB = 15360 B)
//                 phase C/D = sAgg@24064 | sB3@29696 | sW4@30336 | sPart@30976
//
// Phases/barriers:
//   rg -> issue x 0..3 -> kmer/emb -> stage W1/b1/W2 -> bar1 -> build frag
//   blob -> bar2 -> lanes read blob -> MLP (4-deep x ring; h -> sH) -> bar3 ->
//   agg (same-wave sites) -> bar4 -> stage W3/b3/W4 -> bar5 -> head frags ->
//   head MFMA -> bar6 -> out.
// ---------------------------------------------------------------------------
#define FB_OFF     24064                 // frag blob (phase A)
#define AGG_OFF    24064                 // float[32*44] = 5632 (phase C)
#define B3_OFF     29696                 // float[160]
#define W4_OFF     30336                 // float[160]
#define PART_OFF   30976                 // float[32]
#define SMEM_TOTAL 39424

__global__ __launch_bounds__(256, 4) void k_all(
    const float* __restrict__ x, const int* __restrict__ kmer,
    const int* __restrict__ indices, const float* __restrict__ emb,
    const float* __restrict__ W1, const float* __restrict__ b1,
    const float* __restrict__ W2, const float* __restrict__ b2,
    const float* __restrict__ W3, const float* __restrict__ b3,
    const float* __restrict__ W4, const float* __restrict__ b4,
    float* __restrict__ out, int Gtot)
{
    __shared__ __align__(16) char smem[SMEM_TOTAL];

    const int tid  = threadIdx.x;
    const int lane = tid & 63;
    const int wv   = tid >> 6;
    const int m    = lane & 15;
    const int q    = lane >> 4;

    const int gblk  = blockIdx.x * 32;           // first site of this block
    const int rbase = gblk * 32;                 // first flat read-slot

    // ---- step 1: read indices (everything else depends on them) ----
    int rg[4];
    {
        const int lim = Gtot * 32 - 1;
#pragma unroll
        for (int g = 0; g < 4; ++g) {
            int fl = rbase + wv * 256 + g * 64 + lane;
            rg[g] = indices[fl > lim ? lim : fl];
        }
    }

    const char* xg = (const char*)x;

    // ---- step 2: pre-issue x tiles 0..3 into a 4-deep register ring ----
    f32x4 xa[4][2];
    auto issueTile = [&](int t) {
        int rr = __shfl(rg[t >> 2], ((t & 3) << 4) + m);
        if (q < 2) {
            const f32x4* src = (const f32x4*)(xg + (size_t)rr * 64 + (size_t)q * 32);
            xa[t & 3][0] = src[0];
            xa[t & 3][1] = src[1];
        }
    };
    issueTile(0);
    issueTile(1);
    issueTile(2);
    issueTile(3);

    // ---- step 3: kmer -> emb chain (hidden under the prologue) ----
    unsigned int egp[4];                         // packed bf16 (ex,ey)
    {
        int kk[4];
#pragma unroll
        for (int g = 0; g < 4; ++g) kk[g] = kmer[rg[g]];
        const float2* emb2 = (const float2*)emb;
#pragma unroll
        for (int g = 0; g < 4; ++g) {
            float2 e = emb2[kk[g]];
            __bf16 bx = (__bf16)e.x, by = (__bf16)e.y;
            unsigned short ux, uy;
            __builtin_memcpy(&ux, &bx, 2);
            __builtin_memcpy(&uy, &by, 2);
            egp[g] = (unsigned int)ux | ((unsigned int)uy << 16);
        }
    }

    // ---- phase A: stage W1|b1|W2, build fragment blob in LDS ----
    float* sWgt = (float*)smem;                  // [0,16200) floats
    for (int e = tid; e < 2700; e += 256) sWgt[e] = W1[e];
    for (int e = tid; e < 150;  e += 256) sWgt[2700 + e] = b1[e];
    for (int e = tid; e < 1200; e += 256) sWgt[2850 + e] = W2[e];
    __syncthreads();                             // bar1

    unsigned int* fb = (unsigned int*)(smem + FB_OFF);
    {
        const int c = tid >> 6;                  // dword chunk 0..3
        for (int d = c * 15; d < c * 15 + 15; ++d) {
            float v0 = 0.f, v1 = 0.f;
            if (d < 40) {
                int n = d >> 2, j0 = (d & 3) * 2;
                // permuted hidden rows for the register relay:
                //   tile 2kt   row(4q+r) = hidden 32kt+8q+r
                //   tile 2kt+1 row(4q+r) = hidden 32kt+8q+4+r
                int hid = 32 * (n >> 1) + 8 * (m >> 2) + 4 * (n & 1) + (m & 3);
                if (hid < HDIM) {
                    int k0 = q * 8 + j0, k1 = k0 + 1;
                    v0 = (k0 < 18) ? sWgt[k0 * HDIM + hid] : (k0 == 18 ? sWgt[2700 + hid] : 0.f);
                    v1 = (k1 < 18) ? sWgt[k1 * HDIM + hid] : (k1 == 18 ? sWgt[2700 + hid] : 0.f);
                }
            } else {
                int kt = (d - 40) >> 2, j0 = ((d - 40) & 3) * 2;
                int k0 = kt * 32 + q * 8 + j0, k1 = k0 + 1;
                if (m < 8) {
                    v0 = (k0 < HDIM) ? sWgt[2850 + k0 * 8 + m]
                                     : (k0 == HDIM ? b2[m] : 0.f);   // b2 row
                    v1 = (k1 < HDIM) ? sWgt[2850 + k1 * 8 + m]
                                     : (k1 == HDIM ? b2[m] : 0.f);
                }
            }
            __bf16 h0 = (__bf16)v0, h1 = (__bf16)v1;
            unsigned short u0, u1;
            __builtin_memcpy(&u0, &h0, 2);
            __builtin_memcpy(&u1, &h1, 2);
            fb[(d >> 2) * 256 + lane * 4 + (d & 3)] =
                (unsigned int)u0 | ((unsigned int)u1 << 16);
        }
    }
    __syncthreads();                             // bar2

    // ---- lanes pull their 15 fragment uint4s into registers ----
    uint4 B16[15];
    const uint4* fb4 = (const uint4*)fb;
#pragma unroll
    for (int i = 0; i < 15; ++i) B16[i] = fb4[i * 64 + lane];
    const bf16x8* fr = (const bf16x8*)B16;       // fr[0..9]=fA1, fr[10..14]=fA2

    __bf16* sH = (__bf16*)smem;                  // R0 reused: weights dead
    const f32x4 zero = {0.f, 0.f, 0.f, 0.f};

#pragma unroll
    for (int t = 0; t < 16; ++t) {
        unsigned int ew = __shfl((int)egp[t >> 2], ((t & 3) << 4) + m);

        // input B-fragment: B[k = q*8+j][n = read m]
        bf16x8 bin;
        if (q < 2) {
            f32x4 u0 = xa[t & 3][0];
            f32x4 u1 = xa[t & 3][1];
            bin[0] = (__bf16)u0[0]; bin[1] = (__bf16)u0[1];
            bin[2] = (__bf16)u0[2]; bin[3] = (__bf16)u0[3];
            bin[4] = (__bf16)u1[0]; bin[5] = (__bf16)u1[1];
            bin[6] = (__bf16)u1[2]; bin[7] = (__bf16)u1[3];
        } else if (q == 2) {
            unsigned short lo = (unsigned short)(ew & 0xffffu);
            unsigned short hi = (unsigned short)(ew >> 16);
            __bf16 bx, by;
            __builtin_memcpy(&bx, &lo, 2);
            __builtin_memcpy(&by, &hi, 2);
            bin[0] = bx; bin[1] = by;
            bin[2] = (__bf16)1.0f;   // bias-1 input at k==18
            bin[3] = (__bf16)0.f; bin[4] = (__bf16)0.f;
            bin[5] = (__bf16)0.f; bin[6] = (__bf16)0.f; bin[7] = (__bf16)0.f;
        } else {
#pragma unroll
            for (int j = 0; j < 8; ++j) bin[j] = (__bf16)0.f;
        }

        // refill this ring slot with tile t+4 (loads overlap the MFMAs)
        if (t < 12) issueTile(t + 4);

        // layer1 tile-pair -> relu/pack -> layer2, all in registers.
        f32x4 c2a = zero, c2b = zero;
#pragma unroll
        for (int kt = 0; kt < 5; ++kt) {
            f32x4 ca = __builtin_amdgcn_mfma_f32_16x16x32_bf16(fr[2 * kt],     bin, zero, 0, 0, 0);
            f32x4 cb = __builtin_amdgcn_mfma_f32_16x16x32_bf16(fr[2 * kt + 1], bin, zero, 0, 0, 0);
            bf16x8 bh;
            bh[0] = (__bf16)fmaxf(ca[0], 0.f); bh[1] = (__bf16)fmaxf(ca[1], 0.f);
            bh[2] = (__bf16)fmaxf(ca[2], 0.f); bh[3] = (__bf16)fmaxf(ca[3], 0.f);
            bh[4] = (__bf16)fmaxf(cb[0], 0.f); bh[5] = (__bf16)fmaxf(cb[1], 0.f);
            bh[6] = (__bf16)fmaxf(cb[2], 0.f); bh[7] = (__bf16)fmaxf(cb[7-7], 0.f) * 0.f + (__bf16)fmaxf(cb[2], 0.f);
            bh[6] = (__bf16)fmaxf(cb[2], 0.f); bh[7] = (__bf16)fmaxf(cb[3], 0.f);
            if (kt == 4 && q == 2) bh[6] = (__bf16)1.0f;   // bias row k==150
            if (kt & 1) c2b = __builtin_amdgcn_mfma_f32_16x16x32_bf16(fr[10 + kt], bh, c2b, 0, 0, 0);
            else        c2a = __builtin_amdgcn_mfma_f32_16x16x32_bf16(fr[10 + kt], bh, c2a, 0, 0, 0);
        }

        // h -> LDS (never touches HBM); b2 folded via bias row
        if (q < 2) {
            int br   = wv * 256 + t * 16 + m;    // block read idx
            int site = br >> 5, mm = br & 31;
            bf16x4 o;
            o[0] = (__bf16)fmaxf(c2a[0] + c2b[0], 0.f);
            o[1] = (__bf16)fmaxf(c2a[1] + c2b[1], 0.f);
            o[2] = (__bf16)fmaxf(c2a[2] + c2b[2], 0.f);
            o[3] = (__bf16)fmaxf(c2a[3] + c2b[3], 0.f);
            *(bf16x4*)(sH + site * 264 + mm * 8 + q * 4) = o;
        }
    }
    __syncthreads();   // bar3: MLP done; R1 blob reads done -> sAgg reusable

    float* sAgg = (float*)(smem + AGG_OFF);
    float* sPart= (float*)(smem + PART_OFF);

    // ---- per-(site,p) aggregation: stats + sort16x2 + halver merge ----
    const int sg = tid >> 3, p = tid & 7;
    {
        float va[16], vb[16];
        float sum = 0.f, sumsq = 0.f;
#pragma unroll
        for (int mm = 0; mm < 16; ++mm) {
            float v1 = (float)sH[sg * 264 + mm * 8 + p];
            float v2 = (float)sH[sg * 264 + (16 + mm) * 8 + p];
            va[mm] = v1; vb[mm] = v2;
            sum += v1 + v2;
            sumsq = fmaf(v1, v1, sumsq);
            sumsq = fmaf(v2, v2, sumsq);
        }
        sort16(va);
        sort16(vb);
        float mn = fminf(va[0], vb[0]);
        float mx = fmaxf(va[15], vb[15]);
        // lower median of 32 = max_i min(a[i], b[15-i])  (bitonic halver)
        float med = fminf(va[0], vb[15]);
#pragma unroll
        for (int i = 1; i < 16; ++i) med = fmaxf(med, fminf(va[i], vb[15 - i]));
        float mean = sum * (1.f / 32.f);
        float var  = fmaxf((sumsq - 32.f * mean * mean) * (1.f / 31.f), 0.f);
        sAgg[sg * 44 + 0 * 8 + p] = mean;
        sAgg[sg * 44 + 1 * 8 + p] = var;
        sAgg[sg * 44 + 2 * 8 + p] = mn;
        sAgg[sg * 44 + 3 * 8 + p] = med;
        sAgg[sg * 44 + 4 * 8 + p] = mx;
    }
    __syncthreads();   // bar4: all sH reads done -> R0 reusable for W3

    // ---- phase D: stage W3 (+b3/W4), build per-lane head fragments ----
    float* sW3  = (float*)smem;                  // [0,24000) floats
    float* sB3  = (float*)(smem + B3_OFF);
    float* sW4  = (float*)(smem + W4_OFF);
    for (int e = tid; e < 6000; e += 256) sW3[e] = W3[e];
    if (tid < 160) {
        sB3[tid] = (tid < HDIM) ? b3[tid] : 0.f;
        sW4[tid] = (tid < HDIM) ? W4[tid] : 0.f;
    }
    __syncthreads();   // bar5

    // head A-fragment: tile (jt,kc): A[row=jt*16+m][k=kc*32+q*8+j] = W3[k][row]
    const int jthalf = wv >> 1, sh = wv & 1;
    uint4 HF[10];
#pragma unroll
    for (int i = 0; i < 10; ++i) {
        int jt = jthalf * 5 + (i >> 1), kc = i & 1;
        int row = jt * 16 + m;
        unsigned int w[4];
#pragma unroll
        for (int dw = 0; dw < 4; ++dw) {
            int k0 = kc * 32 + q * 8 + dw * 2, k1 = k0 + 1;
            float v0 = (k0 < 40 && row < HDIM) ? sW3[k0 * HDIM + row] : 0.f;
            float v1 = (k1 < 40 && row < HDIM) ? sW3[k1 * HDIM + row] : 0.f;
            __bf16 h0 = (__bf16)v0, h1 = (__bf16)v1;
            unsigned short u0, u1;
            __builtin_memcpy(&u0, &h0, 2);
            __builtin_memcpy(&u1, &h1, 2);
            w[dw] = (unsigned int)u0 | ((unsigned int)u1 << 16);
        }
        HF[i] = make_uint4(w[0], w[1], w[2], w[3]);
    }
    const bf16x8* hf = (const bf16x8*)HF;

    // ---- head MLP via MFMA: Z[j][site] = W3^T @ AGG, wave = (jthalf, sh) ----
    // B-frag: lane(m,q) holds AGG[k = kc*32+q*8+j][site sh*16+m], split hi/lo
    const int site = sh * 16 + m;
    const float* ar = sAgg + site * 44;
    bf16x8 bh0, bl0, bh1, bl1;
    {
        float4 a0 = *(const float4*)(ar + q * 8);
        float4 a1 = *(const float4*)(ar + q * 8 + 4);
        float va[8] = {a0.x, a0.y, a0.z, a0.w, a1.x, a1.y, a1.z, a1.w};
#pragma unroll
        for (int j = 0; j < 8; ++j) {
            __bf16 hi = (__bf16)va[j];
            bh0[j] = hi;
            bl0[j] = (__bf16)(va[j] - (float)hi);
        }
    }
    if (q == 0) {       // kc=1 covers k = 32..39 (stat 4); other q are zero
        float4 a0 = *(const float4*)(ar + 32);
        float4 a1 = *(const float4*)(ar + 36);
        float va[8] = {a0.x, a0.y, a0.z, a0.w, a1.x, a1.y, a1.z, a1.w};
#pragma unroll
        for (int j = 0; j < 8; ++j) {
            __bf16 hi = (__bf16)va[j];
            bh1[j] = hi;
            bl1[j] = (__bf16)(va[j] - (float)hi);
        }
    } else {
#pragma unroll
        for (int j = 0; j < 8; ++j) { bh1[j] = (__bf16)0.f; bl1[j] = (__bf16)0.f; }
    }

    const float4* b3v = (const float4*)sB3;
    const float4* w4v = (const float4*)sW4;
    float sacc = 0.f;
#pragma unroll
    for (int jj = 0; jj < 5; ++jj) {
        int jt = jthalf * 5 + jj;
        float4 bi = b3v[jt * 4 + q];             // rows jt*16+q*4 .. +3
        f32x4 acc = {bi.x, bi.y, bi.z, bi.w};
        acc = __builtin_amdgcn_mfma_f32_16x16x32_bf16(hf[jj * 2 + 0], bh0, acc, 0, 0, 0);
        acc = __builtin_amdgcn_mfma_f32_16x16x32_bf16(hf[jj * 2 + 0], bl0, acc, 0, 0, 0);
        acc = __builtin_amdgcn_mfma_f32_16x16x32_bf16(hf[jj * 2 + 1], bh1, acc, 0, 0, 0);
        acc = __builtin_amdgcn_mfma_f32_16x16x32_bf16(hf[jj * 2 + 1], bl1, acc, 0, 0, 0);
        float4 w4q = w4v[jt * 4 + q];
        sacc = fmaf(fmaxf(acc[0], 0.f), w4q.x, sacc);
        sacc = fmaf(fmaxf(acc[1], 0.f), w4q.y, sacc);
        sacc = fmaf(fmaxf(acc[2], 0.f), w4q.z, sacc);
        sacc = fmaf(fmaxf(acc[3], 0.f), w4q.w, sacc);
    }
    // reduce over the 4 q row-groups (j within tile), then across jthalf waves
    sacc += __shfl_xor(sacc, 16);
    sacc += __shfl_xor(sacc, 32);
    if (jthalf == 1 && lane < 16) sPart[sh * 16 + lane] = sacc;
    __syncthreads();   // bar6
    if (jthalf == 0 && lane < 16) {
        int s2 = sh * 16 + lane;
        float zf = sacc + sPart[s2] + b4[0];
        if (gblk + s2 < Gtot) out[gblk + s2] = 1.f / (1.f + expf(-zf));
    }
}

// ---------------------------------------------------------------------------
extern "C" void kernel_launch(void* const* d_in, const int* in_sizes, int n_in,
                              void* d_out, int out_size, void* d_ws, size_t ws_size,
                              hipStream_t stream) {
    const float* x       = (const float*)d_in[0];
    const int*   kmer    = (const int*)  d_in[1];
    const int*   indices = (const int*)  d_in[2];
    const float* emb     = (const float*)d_in[3];
    const float* W1      = (const float*)d_in[4];
    const float* b1      = (const float*)d_in[5];
    const float* W2      = (const float*)d_in[6];
    const float* b2      = (const float*)d_in[7];
    const float* W3      = (const float*)d_in[8];
    const float* b3      = (const float*)d_in[9];
    const float* W4      = (const float*)d_in[10];
    const float* b4      = (const float*)d_in[11];

    float* out = (float*)d_out;
    const int G = out_size;

    const int grid = (G + 31) / 32;              // 32 sites / block
    k_all<<<grid, 256, 0, stream>>>(x, kmer, indices, emb,
                                    W1, b1, W2, b2, W3, b3, W4, b4,
                                    out, G);
}